// Round 14
// baseline (164.592 us; speedup 1.0000x reference)
//
#include <hip/hip_runtime.h>
#include <hip/hip_bf16.h>

// FeastNet fused: B=2, V=50000, NB=16, C=64, K=8, O=64
// out[b,v,o] = inv_deg[v] * sum_{c,k} M[c,k] * W[c,k,o]
//   M[c,k]   = sum_n patches[b,v,n,c] * q[b,v,n,k]
//   q        = softmax_k( xu[self] - xu[neighbor] ),  xu = x @ u
// v6 = v5 with (a) explicit int off[16] so a[] dies after Phase A (v4's
// 140-reg live set was a[]+hoisted addrs both live), (b) launch_bounds
// (256,4): live ~92 fits the 128-reg budget with margin -> 4 blocks/CU
// static vs 3. Spill canary: WRITE_SIZE must stay ~25MB.

constexpr int BB = 2;
constexpr int VV = 50000;
#define NB 16
#define CC 64
#define KK 8
#define OO 64
#define TV 16  // vertices per workgroup (256 threads, 16 threads/vertex)

typedef __attribute__((ext_vector_type(8))) short bf16x8;  // 8 bf16 (4 VGPRs)
typedef __attribute__((ext_vector_type(4))) float f32x4;

static __device__ __forceinline__ short f2b(float f) {
    __hip_bfloat16 h = __float2bfloat16(f);  // RNE
    return *reinterpret_cast<short*>(&h);
}

// ---- K0 merged prep: xu (blocks [0,XUB)) + Wb prep (blocks [XUB, XUB+WPB)) ----
constexpr int XUB = (BB * VV * 2 + 255) / 256;  // 2 threads per row -> 782
constexpr int WPB = (CC * KK * OO) / 256;       // 128

__global__ void prep_kernel(const float* __restrict__ x,
                            const float* __restrict__ u,
                            float* __restrict__ xu,
                            const float* __restrict__ W,
                            short* __restrict__ Wb) {
    int blk = blockIdx.x;
    if (blk < XUB) {
        // xu[g,k] = sum_c x[g,c]*u[c,k]; thread = (row g, k-half)
        int t = blk * 256 + threadIdx.x;
        if (t >= BB * VV * 2) return;
        int g = t >> 1, half = t & 1;
        const float4* xr =
            reinterpret_cast<const float4*>(x) + (size_t)g * (CC / 4);
        const float4* u4 = reinterpret_cast<const float4*>(u);
        float a0 = 0.f, a1 = 0.f, a2 = 0.f, a3 = 0.f;
#pragma unroll
        for (int c4 = 0; c4 < CC / 4; ++c4) {
            float4 xv = xr[c4];
            float4 u0 = u4[(c4 * 4 + 0) * 2 + half];
            float4 u1 = u4[(c4 * 4 + 1) * 2 + half];
            float4 u2 = u4[(c4 * 4 + 2) * 2 + half];
            float4 u3 = u4[(c4 * 4 + 3) * 2 + half];
            a0 = fmaf(xv.x, u0.x, a0); a1 = fmaf(xv.x, u0.y, a1);
            a2 = fmaf(xv.x, u0.z, a2); a3 = fmaf(xv.x, u0.w, a3);
            a0 = fmaf(xv.y, u1.x, a0); a1 = fmaf(xv.y, u1.y, a1);
            a2 = fmaf(xv.y, u1.z, a2); a3 = fmaf(xv.y, u1.w, a3);
            a0 = fmaf(xv.z, u2.x, a0); a1 = fmaf(xv.z, u2.y, a1);
            a2 = fmaf(xv.z, u2.z, a2); a3 = fmaf(xv.z, u2.w, a3);
            a0 = fmaf(xv.w, u3.x, a0); a1 = fmaf(xv.w, u3.y, a1);
            a2 = fmaf(xv.w, u3.z, a2); a3 = fmaf(xv.w, u3.w, a3);
        }
        reinterpret_cast<float4*>(xu)[(size_t)g * 2 + half] =
            make_float4(a0, a1, a2, a3);
    } else {
        // W (C,K*O) f32 -> Wb bf16 in MFMA B-fragment order.
        // Wb[((ks*4+gct)*64+l)*8+e] = W[(ks*32+(l>>4)*8+e)*OO + gct*16+(l&15)]
        int dst = (blk - XUB) * 256 + threadIdx.x;
        int e = dst & 7;
        int l = (dst >> 3) & 63;
        int ctk = dst >> 9;
        int gct = ctk & 3;
        int ks = ctk >> 2;
        int ck = ks * 32 + (l >> 4) * 8 + e;
        int o = gct * 16 + (l & 15);
        Wb[dst] = f2b(W[ck * OO + o]);
    }
}

// ---------------- K2: fused q + M-build + MFMA contraction ----------------
__global__ __launch_bounds__(256, 4) void feast_fused(
    const float* __restrict__ x, const int* __restrict__ adj,
    const float* __restrict__ xu, const short* __restrict__ Wb,
    float* __restrict__ out) {
    // 16KB: first 8KB holds qlds fp32 [n=16][vl=16][k=8]; then all 16KB
    // reused as M bf16 [16][512] (row = 1024B = 64 16B-slots, swizzled).
    __shared__ char smem[TV * 1024];
    __shared__ float sInvd[TV];

    int t = threadIdx.x;
    int b = blockIdx.y;
    int v0 = blockIdx.x * TV;
    int vl = t >> 4;  // vertex local 0..15
    int jj = t & 15;  // Phase A: neighbor idx; Phase C: channel-quad idx
    int v = v0 + vl;  // VV % TV == 0: always valid

    float* qlds = reinterpret_cast<float*>(smem);
    const float4* xu4 = reinterpret_cast<const float4*>(xu);
    const float4* x4 = reinterpret_cast<const float4*>(x);

    // ---- adj row -> int float4-offsets off[16]; a[] dies here ----
    int off[NB];
    float deg = 0.f;
    {
        const int4* arow = reinterpret_cast<const int4*>(adj + (size_t)v * NB);
#pragma unroll
        for (int n4 = 0; n4 < 4; ++n4) {
            int4 t4 = arow[n4];
            int aa[4] = {t4.x, t4.y, t4.z, t4.w};
#pragma unroll
            for (int s = 0; s < 4; ++s) {
                int an = aa[s];
                deg += (an != 0) ? 1.f : 0.f;
                off[n4 * 4 + s] = (b * VV + (an ? an - 1 : 0)) * 16 + jj;
            }
        }
    }
    if (jj == 0) sInvd[vl] = (deg > 0.f) ? (1.f / deg) : 0.f;

    // ---- Phase A: softmax q for neighbor jj of vertex vl -> qlds ----
    {
        int gs = b * VV + v;
        float4 s0 = xu4[(size_t)gs * 2], s1 = xu4[(size_t)gs * 2 + 1];
        int an = adj[(size_t)v * NB + jj];  // direct load (no dyn reg index)
        int g = b * VV + (an ? an - 1 : 0);
        float4 n0 = xu4[(size_t)g * 2], n1 = xu4[(size_t)g * 2 + 1];
        float l8[KK] = {s0.x - n0.x, s0.y - n0.y, s0.z - n0.z, s0.w - n0.w,
                        s1.x - n1.x, s1.y - n1.y, s1.z - n1.z, s1.w - n1.w};
        float mx = l8[0];
#pragma unroll
        for (int k = 1; k < KK; ++k) mx = fmaxf(mx, l8[k]);
        float e8[KK];
        float sum = 0.f;
#pragma unroll
        for (int k = 0; k < KK; ++k) {
            e8[k] = __expf(l8[k] - mx);
            sum += e8[k];
        }
        float r = an ? (1.f / sum) : 0.f;
        f32x4* qp = reinterpret_cast<f32x4*>(qlds + jj * 128 + vl * 8);
        qp[0] = (f32x4){e8[0] * r, e8[1] * r, e8[2] * r, e8[3] * r};
        qp[1] = (f32x4){e8[4] * r, e8[5] * r, e8[6] * r, e8[7] * r};
    }

// ---- Phase C: acc[c=4][k=8] over 16 neighbors, depth-6 prefetch ----
#define CONS(n, P)                                                             \
    {                                                                          \
        const f32x4* qv =                                                      \
            reinterpret_cast<const f32x4*>(qlds + (n) * 128 + vl * 8);         \
        f32x4 q0 = qv[0];                                                      \
        f32x4 q1 = qv[1];                                                      \
        float p[4] = {P.x, P.y, P.z, P.w};                                     \
        _Pragma("unroll") for (int c = 0; c < 4; ++c) {                        \
            _Pragma("unroll") for (int k = 0; k < 4; ++k) {                    \
                acc[c][k] = fmaf(p[c], q0[k], acc[c][k]);                      \
                acc[c][k + 4] = fmaf(p[c], q1[k], acc[c][k + 4]);              \
            }                                                                  \
        }                                                                      \
    }

    float4 P0, P1, P2, P3, P4, P5;
    P0 = x4[off[0]];
    P1 = x4[off[1]];
    P2 = x4[off[2]];
    P3 = x4[off[3]];
    P4 = x4[off[4]];
    P5 = x4[off[5]];
    __syncthreads();  // qlds visible; first 6 gathers in flight across barrier

    float acc[4][KK];
#pragma unroll
    for (int c = 0; c < 4; ++c)
#pragma unroll
        for (int k = 0; k < KK; ++k) acc[c][k] = 0.f;

    CONS(0, P0) P0 = x4[off[6]];
    CONS(1, P1) P1 = x4[off[7]];
    CONS(2, P2) P2 = x4[off[8]];
    CONS(3, P3) P3 = x4[off[9]];
    CONS(4, P4) P4 = x4[off[10]];
    CONS(5, P5) P5 = x4[off[11]];
    CONS(6, P0) P0 = x4[off[12]];
    CONS(7, P1) P1 = x4[off[13]];
    CONS(8, P2) P2 = x4[off[14]];
    CONS(9, P3) P3 = x4[off[15]];
    CONS(10, P4)
    CONS(11, P5)
    CONS(12, P0)
    CONS(13, P1)
    CONS(14, P2)
    CONS(15, P3)

    __syncthreads();  // all q reads done -> safe to overwrite smem with M

    // ---- M -> bf16 LDS; slot = channel c = jj*4+s (8 k-values per slot),
    //      swizzle slot2 = slot ^ ((slot>>3)&7) ^ (row&7) (same as read side)
#pragma unroll
    for (int s = 0; s < 4; ++s) {
        bf16x8 w;
#pragma unroll
        for (int k = 0; k < KK; ++k) w[k] = f2b(acc[s][k]);
        int slot = jj * 4 + s;
        int slot2 = slot ^ ((slot >> 3) & 7) ^ (vl & 7);
        *reinterpret_cast<bf16x8*>(smem + vl * 1024 + slot2 * 16) = w;
    }
    __syncthreads();

    // ---- Phase 2: out[16x64] = M[16x512] @ Wb[512x64] via MFMA ----
    {
        int wid = t >> 6;  // wave 0..3 = col tile (16 cols each)
        int l = t & 63;
        int r = l & 15;  // A-frag row

        f32x4 acc2 = (f32x4){0.f, 0.f, 0.f, 0.f};
        const bf16x8* WbV = reinterpret_cast<const bf16x8*>(Wb);

#pragma unroll
        for (int ks = 0; ks < 16; ++ks) {
            int ks4h = ks * 4 + (l >> 4);
            int slotA = ks4h ^ ((ks4h >> 3) & 7) ^ (r & 7);
            bf16x8 afrag = *reinterpret_cast<const bf16x8*>(
                smem + r * 1024 + slotA * 16);
            bf16x8 bfrag = WbV[(ks * 4 + wid) * 64 + l];
            acc2 = __builtin_amdgcn_mfma_f32_16x16x32_bf16(afrag, bfrag, acc2,
                                                           0, 0, 0);
        }

        // C/D layout: col = l&15, row = (l>>4)*4 + reg
        int col = wid * 16 + (l & 15);
#pragma unroll
        for (int jr = 0; jr < 4; ++jr) {
            int rowl = (l >> 4) * 4 + jr;
            out[((size_t)b * VV + v0 + rowl) * OO + col] =
                acc2[jr] * sInvd[rowl];
        }
    }
}

extern "C" void kernel_launch(void* const* d_in, const int* in_sizes, int n_in,
                              void* d_out, int out_size, void* d_ws,
                              size_t ws_size, hipStream_t stream) {
    const float* x = (const float*)d_in[0];  // (B,V,C) f32
    const float* u = (const float*)d_in[1];  // (C,K)   f32
    const float* W = (const float*)d_in[2];  // (C,K*O) f32
    const int* adj = (const int*)d_in[3];    // (V,NB)  i32
    float* out = (float*)d_out;              // (B,V,O) f32

    float* xu = (float*)d_ws;  // (B*V, K) f32 = 3.2 MB
    short* Wb = (short*)((char*)d_ws + (size_t)BB * VV * KK * sizeof(float));

    prep_kernel<<<XUB + WPB, 256, 0, stream>>>(x, u, xu, W, Wb);
    dim3 g(VV / TV, BB);
    feast_fused<<<g, 256, 0, stream>>>(x, adj, xu, Wb, out);
}